// Round 4
// baseline (259.865 us; speedup 1.0000x reference)
//
#include <hip/hip_runtime.h>

#define DM 1024
#define NW 16384

// ws layout (float offsets)
#define OFF_C    1024       // 16*1024
#define OFF_D0   17408      // 16
#define OFF_S    17424      // 16 heads, stride 16 floats (64B line each) = 256
#define OFF_X    17696      // 1024
#define OFF_W    18720      // 16*1024
#define OFF_E    36864      // e[NW][16] = 262144
#define OFF_PART 299008     // partials [128][16][1024] = 2097152

// out[r] = dot(W[r,:], v) + b[r]   — one wave per row, 1024 waves
__global__ __launch_bounds__(256) void k_rowdot(const float* __restrict__ W,
                                                const float* __restrict__ v,
                                                const float* __restrict__ b,
                                                float* __restrict__ out) {
  const int wave = (blockIdx.x * 256 + threadIdx.x) >> 6;
  const int lane = threadIdx.x & 63;
  const float* row = W + (size_t)wave * DM + 4 * lane;
  float s = 0.f;
#pragma unroll
  for (int j = 0; j < 4; ++j) {
    float4 a = *(const float4*)(row + j * 256);
    float4 x = *(const float4*)(v + j * 256 + 4 * lane);
    s += a.x * x.x + a.y * x.y + a.z * x.z + a.w * x.w;
  }
#pragma unroll
  for (int off = 32; off; off >>= 1) s += __shfl_xor(s, off, 64);
  if (lane == 0) out[wave] = s + b[wave];
}

// Fused: q_h = query@Wq_h^T + bq (into LDS), then
// c[h,m] = sum_d q_h[d] * Wk[h*64+d, m];  d0[h] = q_h · bk_h.  Also zeroes S.
__global__ __launch_bounds__(256) void k_qck(const float* __restrict__ Wq,
                                             const float* __restrict__ bq,
                                             const float* __restrict__ query,
                                             const float* __restrict__ Wk,
                                             const float* __restrict__ bk,
                                             float* __restrict__ c,
                                             float* __restrict__ d0,
                                             float* __restrict__ S) {
  const int h = blockIdx.x >> 2;
  const int mc = blockIdx.x & 3;
  const int t = threadIdx.x;
  const int lane = t & 63;
  const int wv = t >> 6;
  __shared__ float qh[64];
  if (blockIdx.x == 0 && t < 16) S[t * 16] = 0.f;
  // phase 1: each wave computes 16 rows of q_h
  float4 qv[4];
#pragma unroll
  for (int j = 0; j < 4; ++j) qv[j] = *(const float4*)(query + j * 256 + 4 * lane);
#pragma unroll 1
  for (int i = 0; i < 16; ++i) {
    const int d = 4 * i + wv;
    const int R = h * 64 + d;
    const float* row = Wq + (size_t)R * DM + 4 * lane;
    float s = 0.f;
#pragma unroll
    for (int j = 0; j < 4; ++j) {
      float4 a = *(const float4*)(row + j * 256);
      s += a.x * qv[j].x + a.y * qv[j].y + a.z * qv[j].z + a.w * qv[j].w;
    }
#pragma unroll
    for (int off = 32; off; off >>= 1) s += __shfl_xor(s, off, 64);
    if (lane == 0) qh[d] = s + bq[R];
  }
  __syncthreads();
  // phase 2: c slice
  const int m = mc * 256 + t;
  const float* Wp = Wk + (size_t)(h * 64) * DM + m;
  float s = 0.f;
#pragma unroll 8
  for (int d = 0; d < 64; ++d) s += qh[d] * Wp[(size_t)d * DM];
  c[h * DM + m] = s;
  if (mc == 0 && t == 0) {
    float tt = 0.f;
    for (int d = 0; d < 64; ++d) tt += qh[d] * bk[h * 64 + d];
    d0[h] = tt;
  }
}

// e[n][h] = exp(c[h,:]·key[n,:] + d0[h]); S[h*16] += per-wave partial sums.
// Wave owns 4 heads: c-fragment lives in VGPRs. No softmax max (scores bounded).
__global__ __launch_bounds__(256, 3) void k_scores(const float* __restrict__ key,
                                                   const float* __restrict__ c,
                                                   const float* __restrict__ d0,
                                                   float* __restrict__ e,
                                                   float* __restrict__ S) {
  const int lane = threadIdx.x & 63;
  const int wv = threadIdx.x >> 6;       // 0..3
  const int hbase = wv * 4;
  const int n0 = blockIdx.x * 16;        // grid 1024 -> 16 rows/block
  float4 cf[4][4];
#pragma unroll
  for (int hh = 0; hh < 4; ++hh)
#pragma unroll
    for (int j = 0; j < 4; ++j)
      cf[hh][j] = *(const float4*)(c + (size_t)(hbase + hh) * DM + j * 256 + 4 * lane);
  const int hl = (lane >> 4) & 3;
  const float dh = d0[hbase + hl];
  const bool hi5 = (lane & 32) != 0;
  const bool hi4 = (lane & 16) != 0;
  const bool writer = (lane & 15) == 0;
  float Ssum = 0.f;
  for (int r = 0; r < 16; ++r) {
    const int n = n0 + r;
    const float* kp = key + (size_t)n * DM + 4 * lane;
    float4 k0 = *(const float4*)(kp + 0);
    float4 k1 = *(const float4*)(kp + 256);
    float4 k2 = *(const float4*)(kp + 512);
    float4 k3 = *(const float4*)(kp + 768);
    float s[4];
#pragma unroll
    for (int hh = 0; hh < 4; ++hh) {
      s[hh] = cf[hh][0].x * k0.x + cf[hh][0].y * k0.y + cf[hh][0].z * k0.z + cf[hh][0].w * k0.w
            + cf[hh][1].x * k1.x + cf[hh][1].y * k1.y + cf[hh][1].z * k1.z + cf[hh][1].w * k1.w
            + cf[hh][2].x * k2.x + cf[hh][2].y * k2.y + cf[hh][2].z * k2.z + cf[hh][2].w * k2.w
            + cf[hh][3].x * k3.x + cf[hh][3].y * k3.y + cf[hh][3].z * k3.z + cf[hh][3].w * k3.w;
    }
    float keep0 = hi5 ? s[2] : s[0], send0 = hi5 ? s[0] : s[2];
    float v0 = keep0 + __shfl_xor(send0, 32, 64);
    float keep1 = hi5 ? s[3] : s[1], send1 = hi5 ? s[1] : s[3];
    float v1 = keep1 + __shfl_xor(send1, 32, 64);
    float keep = hi4 ? v1 : v0, send = hi4 ? v0 : v1;
    float t = keep + __shfl_xor(send, 16, 64);
    t += __shfl_xor(t, 8, 64);
    t += __shfl_xor(t, 4, 64);
    t += __shfl_xor(t, 2, 64);
    t += __shfl_xor(t, 1, 64);
    t = __expf(t + dh);
    if (writer) {
      e[(size_t)n * 16 + hbase + hl] = t;
      Ssum += t;
    }
  }
  if (writer) atomicAdd(S + (size_t)(hbase + hl) * 16, Ssum);
}

// part[nb][h][m] = sum_{n in 128-row chunk} e[n,h]*value[n,m]  (unnormalized)
// Block = (nb, 256-col slice); 4 waves take 32-row stripes; float4 value loads;
// cross-wave tree-reduce in LDS; wave 0 writes partials.
__global__ __launch_bounds__(256, 2) void k_pv(const float* __restrict__ value,
                                               const float* __restrict__ e,
                                               float* __restrict__ part) {
  const int nb = blockIdx.x >> 2;        // 0..127
  const int mc = blockIdx.x & 3;
  const int lane = threadIdx.x & 63;
  const int wy = threadIdx.x >> 6;       // 0..3 row stripe
  const int col = mc * 256 + lane * 4;
  const int n0 = nb * 128 + wy * 32;
  __shared__ float4 red[2][16][64];      // 32 KB
  float4 acc[16];
#pragma unroll
  for (int h = 0; h < 16; ++h) acc[h] = make_float4(0.f, 0.f, 0.f, 0.f);
  const float* vp = value + (size_t)n0 * DM + col;
  const float* ep = e + (size_t)n0 * 16;
#pragma unroll 4
  for (int r = 0; r < 32; ++r) {
    float4 v = *(const float4*)(vp + (size_t)r * DM);
    const float* __restrict__ er = ep + r * 16;   // wave-uniform -> s_load
#pragma unroll
    for (int h = 0; h < 16; ++h) {
      float p = er[h];
      acc[h].x = fmaf(p, v.x, acc[h].x);
      acc[h].y = fmaf(p, v.y, acc[h].y);
      acc[h].z = fmaf(p, v.z, acc[h].z);
      acc[h].w = fmaf(p, v.w, acc[h].w);
    }
  }
  // tree reduce: (2,3) -> (0,1), then 1 -> 0
  if (wy >= 2) {
#pragma unroll
    for (int h = 0; h < 16; ++h) red[wy - 2][h][lane] = acc[h];
  }
  __syncthreads();
  if (wy < 2) {
#pragma unroll
    for (int h = 0; h < 16; ++h) {
      float4 o = red[wy][h][lane];
      acc[h].x += o.x; acc[h].y += o.y; acc[h].z += o.z; acc[h].w += o.w;
    }
  }
  __syncthreads();
  if (wy == 1) {
#pragma unroll
    for (int h = 0; h < 16; ++h) red[0][h][lane] = acc[h];
  }
  __syncthreads();
  if (wy == 0) {
    float* pp = part + (size_t)nb * (16 * DM) + col;
#pragma unroll
    for (int h = 0; h < 16; ++h) {
      float4 o = red[0][h][lane];
      acc[h].x += o.x; acc[h].y += o.y; acc[h].z += o.z; acc[h].w += o.w;
      *(float4*)(pp + (size_t)h * DM) = acc[h];
    }
  }
}

// w[o] = sum_nb part[nb][o] — 4 threads per output, 32 chunks each, shfl combine
__global__ __launch_bounds__(256) void k_wred(const float* __restrict__ part,
                                              float* __restrict__ w) {
  const int gid = blockIdx.x * 256 + threadIdx.x;  // 0..65535
  const int o = gid >> 2;
  const int q = gid & 3;
  float s = 0.f;
#pragma unroll 8
  for (int i = 0; i < 32; ++i) s += part[(size_t)(q * 32 + i) * 16384 + o];
  s += __shfl_xor(s, 1, 64);
  s += __shfl_xor(s, 2, 64);
  if (q == 0) w[o] = s;
}

// x[r] = dot(Wv[r,:], w[h,:]) / S[h] + bv[r],  h = r>>6 — wave per row
__global__ __launch_bounds__(256) void k_xproj(const float* __restrict__ Wv,
                                               const float* __restrict__ w,
                                               const float* __restrict__ bv,
                                               const float* __restrict__ S,
                                               float* __restrict__ x) {
  const int wave = (blockIdx.x * 256 + threadIdx.x) >> 6;
  const int lane = threadIdx.x & 63;
  const int h = wave >> 6;
  const float* vec = w + (size_t)h * DM;
  const float* row = Wv + (size_t)wave * DM + 4 * lane;
  float s = 0.f;
#pragma unroll
  for (int j = 0; j < 4; ++j) {
    float4 a = *(const float4*)(row + j * 256);
    float4 x4 = *(const float4*)(vec + j * 256 + 4 * lane);
    s += a.x * x4.x + a.y * x4.y + a.z * x4.z + a.w * x4.w;
  }
#pragma unroll
  for (int off = 32; off; off >>= 1) s += __shfl_xor(s, off, 64);
  if (lane == 0) x[wave] = s / S[(size_t)h * 16] + bv[wave];
}

extern "C" void kernel_launch(void* const* d_in, const int* in_sizes, int n_in,
                              void* d_out, int out_size, void* d_ws, size_t ws_size,
                              hipStream_t stream) {
  const float* query = (const float*)d_in[0];
  const float* key   = (const float*)d_in[1];
  const float* value = (const float*)d_in[2];
  const float* Wq    = (const float*)d_in[3];
  const float* bq    = (const float*)d_in[4];
  const float* Wk    = (const float*)d_in[5];
  const float* bk    = (const float*)d_in[6];
  const float* Wv    = (const float*)d_in[7];
  const float* bv    = (const float*)d_in[8];
  const float* Wo    = (const float*)d_in[9];
  const float* bo    = (const float*)d_in[10];
  float* out = (float*)d_out;
  float* ws  = (float*)d_ws;

  k_qck    <<<64,  256, 0, stream>>>(Wq, bq, query, Wk, bk, ws + OFF_C, ws + OFF_D0, ws + OFF_S);
  k_scores <<<1024,256, 0, stream>>>(key, ws + OFF_C, ws + OFF_D0, ws + OFF_E, ws + OFF_S);
  k_pv     <<<512, 256, 0, stream>>>(value, ws + OFF_E, ws + OFF_PART);
  k_wred   <<<256, 256, 0, stream>>>(ws + OFF_PART, ws + OFF_W);
  k_xproj  <<<256, 256, 0, stream>>>(Wv, ws + OFF_W, bv, ws + OFF_S, ws + OFF_X);
  k_rowdot <<<256, 256, 0, stream>>>(Wo, ws + OFF_X, bo, out);
}

// Round 5
// 240.340 us; speedup vs baseline: 1.0812x; 1.0812x over previous
//
#include <hip/hip_runtime.h>

#define DM 1024
#define NW 16384

// ws layout (float offsets)
#define OFF_C    1024       // 16*1024
#define OFF_D0   17408      // 16
#define OFF_S    17424      // 16 heads, stride 16 floats (64B line each) = 256
#define OFF_X    17696      // 1024
#define OFF_W    18720      // 16*1024
#define OFF_E    36864      // e[NW][16] = 262144
#define OFF_PART 299008     // partials [128][16][1024] = 2097152

// out[r] = dot(W[r,:], v) + b[r]   — one wave per row, 1024 waves
__global__ __launch_bounds__(256) void k_rowdot(const float* __restrict__ W,
                                                const float* __restrict__ v,
                                                const float* __restrict__ b,
                                                float* __restrict__ out) {
  const int wave = (blockIdx.x * 256 + threadIdx.x) >> 6;
  const int lane = threadIdx.x & 63;
  const float* row = W + (size_t)wave * DM + 4 * lane;
  float s = 0.f;
#pragma unroll
  for (int j = 0; j < 4; ++j) {
    float4 a = *(const float4*)(row + j * 256);
    float4 x = *(const float4*)(v + j * 256 + 4 * lane);
    s += a.x * x.x + a.y * x.y + a.z * x.z + a.w * x.w;
  }
#pragma unroll
  for (int off = 32; off; off >>= 1) s += __shfl_xor(s, off, 64);
  if (lane == 0) out[wave] = s + b[wave];
}

// Fused: q_h = query@Wq_h^T + bq (into LDS), then
// c[h,m] = sum_d q_h[d] * Wk[h*64+d, m];  d0[h] = q_h · bk_h.  Also zeroes S.
__global__ __launch_bounds__(256) void k_qck(const float* __restrict__ Wq,
                                             const float* __restrict__ bq,
                                             const float* __restrict__ query,
                                             const float* __restrict__ Wk,
                                             const float* __restrict__ bk,
                                             float* __restrict__ c,
                                             float* __restrict__ d0,
                                             float* __restrict__ S) {
  const int h = blockIdx.x >> 2;
  const int mc = blockIdx.x & 3;
  const int t = threadIdx.x;
  const int lane = t & 63;
  const int wv = t >> 6;
  __shared__ float qh[64];
  if (blockIdx.x == 0 && t < 16) S[t * 16] = 0.f;
  // phase 1: each wave computes 16 rows of q_h, 2-row load batches
  float4 qv[4];
#pragma unroll
  for (int j = 0; j < 4; ++j) qv[j] = *(const float4*)(query + j * 256 + 4 * lane);
#pragma unroll 1
  for (int i = 0; i < 16; i += 2) {
    const int d0i = 4 * i + wv;
    const int d1i = 4 * (i + 1) + wv;
    const float* r0 = Wq + (size_t)(h * 64 + d0i) * DM + 4 * lane;
    const float* r1 = Wq + (size_t)(h * 64 + d1i) * DM + 4 * lane;
    float4 a0[4], a1[4];
#pragma unroll
    for (int j = 0; j < 4; ++j) { a0[j] = *(const float4*)(r0 + j * 256);
                                  a1[j] = *(const float4*)(r1 + j * 256); }
    float s0 = 0.f, s1 = 0.f;
#pragma unroll
    for (int j = 0; j < 4; ++j) {
      s0 += a0[j].x * qv[j].x + a0[j].y * qv[j].y + a0[j].z * qv[j].z + a0[j].w * qv[j].w;
      s1 += a1[j].x * qv[j].x + a1[j].y * qv[j].y + a1[j].z * qv[j].z + a1[j].w * qv[j].w;
    }
#pragma unroll
    for (int off = 32; off; off >>= 1) { s0 += __shfl_xor(s0, off, 64);
                                         s1 += __shfl_xor(s1, off, 64); }
    if (lane == 0) { qh[d0i] = s0 + bq[h * 64 + d0i];
                     qh[d1i] = s1 + bq[h * 64 + d1i]; }
  }
  __syncthreads();
  // phase 2: c slice — 8-wide load batches; qh from LDS (no vmcnt drain)
  const int m = mc * 256 + t;
  const float* Wp = Wk + (size_t)(h * 64) * DM + m;
  float s = 0.f;
#pragma unroll 1
  for (int db = 0; db < 8; ++db) {
    float wv8[8];
#pragma unroll
    for (int j = 0; j < 8; ++j) wv8[j] = Wp[(size_t)(db * 8 + j) * DM];
#pragma unroll
    for (int j = 0; j < 8; ++j) s = fmaf(qh[db * 8 + j], wv8[j], s);
  }
  c[h * DM + m] = s;
  if (mc == 0 && t == 0) {
    float tt = 0.f;
    for (int d = 0; d < 64; ++d) tt += qh[d] * bk[h * 64 + d];
    d0[h] = tt;
  }
}

// e[n][h] = exp(c[h,:]·key[n,:] + d0[h]); S[h*16] += per-wave partial sums.
// Wave owns 4 heads (cf in VGPRs). 2-row software-pipelined key loads: next
// batch issued before current batch's butterfly, so HBM latency is covered.
__global__ __launch_bounds__(256, 3) void k_scores(const float* __restrict__ key,
                                                   const float* __restrict__ c,
                                                   const float* __restrict__ d0,
                                                   float* __restrict__ e,
                                                   float* __restrict__ S) {
  const int lane = threadIdx.x & 63;
  const int wv = threadIdx.x >> 6;       // 0..3
  const int hbase = wv * 4;
  const int n0 = blockIdx.x * 16;        // grid 1024 -> 16 rows/block
  float4 cf[4][4];
#pragma unroll
  for (int hh = 0; hh < 4; ++hh)
#pragma unroll
    for (int j = 0; j < 4; ++j)
      cf[hh][j] = *(const float4*)(c + (size_t)(hbase + hh) * DM + j * 256 + 4 * lane);
  const int hl = (lane >> 4) & 3;
  const float dh = d0[hbase + hl];
  const bool hi5 = (lane & 32) != 0;
  const bool hi4 = (lane & 16) != 0;
  const bool writer = (lane & 15) == 0;
  float Ssum = 0.f;
  const float* kbase = key + (size_t)n0 * DM + 4 * lane;
  float4 kb[2][4];
#pragma unroll
  for (int j = 0; j < 4; ++j) {
    kb[0][j] = *(const float4*)(kbase + j * 256);
    kb[1][j] = *(const float4*)(kbase + DM + j * 256);
  }
#pragma unroll
  for (int rr = 0; rr < 8; ++rr) {
    float4 kn[2][4];
    if (rr < 7) {
      const float* kp = kbase + (size_t)(2 * rr + 2) * DM;
#pragma unroll
      for (int j = 0; j < 4; ++j) {
        kn[0][j] = *(const float4*)(kp + j * 256);
        kn[1][j] = *(const float4*)(kp + DM + j * 256);
      }
    }
#pragma unroll
    for (int b = 0; b < 2; ++b) {
      const int n = n0 + 2 * rr + b;
      float s[4];
#pragma unroll
      for (int hh = 0; hh < 4; ++hh) {
        s[hh] = cf[hh][0].x * kb[b][0].x + cf[hh][0].y * kb[b][0].y + cf[hh][0].z * kb[b][0].z + cf[hh][0].w * kb[b][0].w
              + cf[hh][1].x * kb[b][1].x + cf[hh][1].y * kb[b][1].y + cf[hh][1].z * kb[b][1].z + cf[hh][1].w * kb[b][1].w
              + cf[hh][2].x * kb[b][2].x + cf[hh][2].y * kb[b][2].y + cf[hh][2].z * kb[b][2].z + cf[hh][2].w * kb[b][2].w
              + cf[hh][3].x * kb[b][3].x + cf[hh][3].y * kb[b][3].y + cf[hh][3].z * kb[b][3].z + cf[hh][3].w * kb[b][3].w;
      }
      float keep0 = hi5 ? s[2] : s[0], send0 = hi5 ? s[0] : s[2];
      float v0 = keep0 + __shfl_xor(send0, 32, 64);
      float keep1 = hi5 ? s[3] : s[1], send1 = hi5 ? s[1] : s[3];
      float v1 = keep1 + __shfl_xor(send1, 32, 64);
      float keep = hi4 ? v1 : v0, send = hi4 ? v0 : v1;
      float t = keep + __shfl_xor(send, 16, 64);
      t += __shfl_xor(t, 8, 64);
      t += __shfl_xor(t, 4, 64);
      t += __shfl_xor(t, 2, 64);
      t += __shfl_xor(t, 1, 64);
      t = __expf(t + dh);
      if (writer) {
        e[(size_t)n * 16 + hbase + hl] = t;
        Ssum += t;
      }
    }
#pragma unroll
    for (int b = 0; b < 2; ++b)
#pragma unroll
      for (int j = 0; j < 4; ++j) kb[b][j] = kn[b][j];
  }
  if (writer) atomicAdd(S + (size_t)(hbase + hl) * 16, Ssum);
}

// part[nb][h][m] = sum_{n in 128-row chunk} e[n,h]*value[n,m]  (unnormalized)
// e staged in LDS (lgkmcnt — no vmcnt drain); value loads batched 8 deep
// (128 B/lane in flight); cross-wave tree-reduce; wave 0 writes partials.
__global__ __launch_bounds__(256, 2) void k_pv(const float* __restrict__ value,
                                               const float* __restrict__ e,
                                               float* __restrict__ part) {
  const int nb = blockIdx.x >> 2;        // 0..127
  const int mc = blockIdx.x & 3;
  const int t = threadIdx.x;
  const int lane = t & 63;
  const int wy = t >> 6;                 // 0..3 row stripe
  const int col = mc * 256 + lane * 4;
  const int n0 = nb * 128;
  __shared__ float el[128 * 16];         // 8 KB
  __shared__ float4 red[2][16][64];      // 32 KB
  {
    const float4* eg = (const float4*)(e + (size_t)n0 * 16);  // 512 float4
    float4* es = (float4*)el;
    es[t] = eg[t];
    es[t + 256] = eg[t + 256];
  }
  __syncthreads();
  float4 acc[16];
#pragma unroll
  for (int h = 0; h < 16; ++h) acc[h] = make_float4(0.f, 0.f, 0.f, 0.f);
  const float* vp = value + (size_t)(n0 + wy * 32) * DM + col;
  const float* ep = &el[wy * 32 * 16];
#pragma unroll 1
  for (int rb = 0; rb < 4; ++rb) {       // 4 batches of 8 rows
    float4 v[8];
#pragma unroll
    for (int i = 0; i < 8; ++i) v[i] = *(const float4*)(vp + (size_t)(rb * 8 + i) * DM);
#pragma unroll
    for (int i = 0; i < 8; ++i) {
      const float4* er4 = (const float4*)(ep + (rb * 8 + i) * 16);
      float4 e0 = er4[0], e1 = er4[1], e2 = er4[2], e3 = er4[3];
      float4 vv = v[i];
#define FMA4H(H, P) { acc[H].x = fmaf(P, vv.x, acc[H].x); acc[H].y = fmaf(P, vv.y, acc[H].y); \
                      acc[H].z = fmaf(P, vv.z, acc[H].z); acc[H].w = fmaf(P, vv.w, acc[H].w); }
      FMA4H(0,  e0.x) FMA4H(1,  e0.y) FMA4H(2,  e0.z) FMA4H(3,  e0.w)
      FMA4H(4,  e1.x) FMA4H(5,  e1.y) FMA4H(6,  e1.z) FMA4H(7,  e1.w)
      FMA4H(8,  e2.x) FMA4H(9,  e2.y) FMA4H(10, e2.z) FMA4H(11, e2.w)
      FMA4H(12, e3.x) FMA4H(13, e3.y) FMA4H(14, e3.z) FMA4H(15, e3.w)
#undef FMA4H
    }
  }
  // tree reduce: (2,3) -> (0,1), then 1 -> 0
  if (wy >= 2) {
#pragma unroll
    for (int h = 0; h < 16; ++h) red[wy - 2][h][lane] = acc[h];
  }
  __syncthreads();
  if (wy < 2) {
#pragma unroll
    for (int h = 0; h < 16; ++h) {
      float4 o = red[wy][h][lane];
      acc[h].x += o.x; acc[h].y += o.y; acc[h].z += o.z; acc[h].w += o.w;
    }
  }
  __syncthreads();
  if (wy == 1) {
#pragma unroll
    for (int h = 0; h < 16; ++h) red[0][h][lane] = acc[h];
  }
  __syncthreads();
  if (wy == 0) {
    float* pp = part + (size_t)nb * (16 * DM) + col;
#pragma unroll
    for (int h = 0; h < 16; ++h) {
      float4 o = red[0][h][lane];
      acc[h].x += o.x; acc[h].y += o.y; acc[h].z += o.z; acc[h].w += o.w;
      *(float4*)(pp + (size_t)h * DM) = acc[h];
    }
  }
}

// w[o] = sum_nb part[nb][o] — 4 threads per output, 32 chunks each, batched 8
__global__ __launch_bounds__(256) void k_wred(const float* __restrict__ part,
                                              float* __restrict__ w) {
  const int gid = blockIdx.x * 256 + threadIdx.x;  // 0..65535
  const int o = gid >> 2;
  const int q = gid & 3;
  float s = 0.f;
#pragma unroll 1
  for (int ib = 0; ib < 4; ++ib) {
    float x[8];
#pragma unroll
    for (int j = 0; j < 8; ++j) x[j] = part[(size_t)(q * 32 + ib * 8 + j) * 16384 + o];
#pragma unroll
    for (int j = 0; j < 8; ++j) s += x[j];
  }
  s += __shfl_xor(s, 1, 64);
  s += __shfl_xor(s, 2, 64);
  if (q == 0) w[o] = s;
}

// x[r] = dot(Wv[r,:], w[h,:]) / S[h] + bv[r],  h = r>>6 — wave per row
__global__ __launch_bounds__(256) void k_xproj(const float* __restrict__ Wv,
                                               const float* __restrict__ w,
                                               const float* __restrict__ bv,
                                               const float* __restrict__ S,
                                               float* __restrict__ x) {
  const int wave = (blockIdx.x * 256 + threadIdx.x) >> 6;
  const int lane = threadIdx.x & 63;
  const int h = wave >> 6;
  const float* vec = w + (size_t)h * DM;
  const float* row = Wv + (size_t)wave * DM + 4 * lane;
  float s = 0.f;
#pragma unroll
  for (int j = 0; j < 4; ++j) {
    float4 a = *(const float4*)(row + j * 256);
    float4 x4 = *(const float4*)(vec + j * 256 + 4 * lane);
    s += a.x * x4.x + a.y * x4.y + a.z * x4.z + a.w * x4.w;
  }
#pragma unroll
  for (int off = 32; off; off >>= 1) s += __shfl_xor(s, off, 64);
  if (lane == 0) x[wave] = s / S[(size_t)h * 16] + bv[wave];
}

extern "C" void kernel_launch(void* const* d_in, const int* in_sizes, int n_in,
                              void* d_out, int out_size, void* d_ws, size_t ws_size,
                              hipStream_t stream) {
  const float* query = (const float*)d_in[0];
  const float* key   = (const float*)d_in[1];
  const float* value = (const float*)d_in[2];
  const float* Wq    = (const float*)d_in[3];
  const float* bq    = (const float*)d_in[4];
  const float* Wk    = (const float*)d_in[5];
  const float* bk    = (const float*)d_in[6];
  const float* Wv    = (const float*)d_in[7];
  const float* bv    = (const float*)d_in[8];
  const float* Wo    = (const float*)d_in[9];
  const float* bo    = (const float*)d_in[10];
  float* out = (float*)d_out;
  float* ws  = (float*)d_ws;

  k_qck    <<<64,  256, 0, stream>>>(Wq, bq, query, Wk, bk, ws + OFF_C, ws + OFF_D0, ws + OFF_S);
  k_scores <<<1024,256, 0, stream>>>(key, ws + OFF_C, ws + OFF_D0, ws + OFF_E, ws + OFF_S);
  k_pv     <<<512, 256, 0, stream>>>(value, ws + OFF_E, ws + OFF_PART);
  k_wred   <<<256, 256, 0, stream>>>(ws + OFF_PART, ws + OFF_W);
  k_xproj  <<<256, 256, 0, stream>>>(Wv, ws + OFF_W, bv, ws + OFF_S, ws + OFF_X);
  k_rowdot <<<256, 256, 0, stream>>>(Wo, ws + OFF_X, bo, out);
}